// Round 1
// baseline (357.556 us; speedup 1.0000x reference)
//
#include <hip/hip_runtime.h>
#include <hip/hip_bf16.h>

// LSTM_80960133529703: B=16384, T=24, F=7, H=8, L=4; dense 192->1024->2048->4.
// Stage 1: lstm_kernel  (fp32, 8 threads/elem, shfl-based recurrence) -> Y bf16 [B,192] in ws
// Stage 2: gemm<192,false>: H1 = relu(Y @ Wd1^T + b1) bf16 [B,1024] in ws
// Stage 3: init_out: out[b,n] = b3[n]
// Stage 4: gemm<1024,true>: H2-tile = relu(H1 @ Wd2^T + b2); fused GEMM3: atomicAdd(out, H2tile @ Wd3^T)
// ws usage: Y 6,291,456 B + H1 33,554,432 B = 39.85 MB.

typedef __attribute__((ext_vector_type(4))) float f32x4;
typedef __attribute__((ext_vector_type(8))) short bf16x8;

__device__ __forceinline__ ushort f2bf(float f) {
    union { float f; uint u; } v; v.f = f;
    uint u = v.u;
    uint r = (u + 0x7fffu + ((u >> 16) & 1u)) >> 16;   // RNE
    return (ushort)r;
}
__device__ __forceinline__ float bf2f(ushort h) {
    union { uint u; float f; } v; v.u = ((uint)h) << 16;
    return v.f;
}
__device__ __forceinline__ float sigm(float x) { return 1.0f / (1.0f + __expf(-x)); }
__device__ __forceinline__ float tanh_(float x) { return 2.0f / (1.0f + __expf(-2.0f * x)) - 1.0f; }

// ---------------------------------------------------------------- LSTM ----
struct LstmW {
    const float* wih[4];
    const float* whh[4];
    const float* bih[4];
    const float* bhh[4];
};

__device__ __forceinline__ void lstm_step_upper(const float (*wihL)[32], const float (*whhL)[32],
                                                const float* bsL, int j, float hprev,
                                                float& h, float& c) {
    float ai = bsL[j], af = bsL[8 + j], ag = bsL[16 + j], ao = bsL[24 + j];
#pragma unroll
    for (int k = 0; k < 8; ++k) {
        float xv = __shfl(hprev, k, 8);   // layer below, this timestep
        float hv = __shfl(h, k, 8);       // own h, previous timestep (pre-update, lockstep)
        ai += wihL[k][j] * xv + whhL[k][j] * hv;
        af += wihL[k][8 + j] * xv + whhL[k][8 + j] * hv;
        ag += wihL[k][16 + j] * xv + whhL[k][16 + j] * hv;
        ao += wihL[k][24 + j] * xv + whhL[k][24 + j] * hv;
    }
    c = sigm(af) * c + sigm(ai) * tanh_(ag);
    h = sigm(ao) * tanh_(c);
}

__global__ __launch_bounds__(256) void lstm_kernel(const float* __restrict__ x, LstmW p,
                                                   ushort* __restrict__ Y) {
    // weights transposed to [k][row] so lanes (j contiguous) hit distinct banks
    __shared__ float wih[4][8][32];
    __shared__ float whh[4][8][32];
    __shared__ float bs[4][32];
    __shared__ float xs[32][168];   // 32 elems x (24*7)

    const int tid = threadIdx.x;
#pragma unroll
    for (int l = 0; l < 4; ++l) {
        const int in = (l == 0) ? 7 : 8;
        for (int i = tid; i < 32 * in; i += 256) {
            int r = i / in, k = i - r * in;
            wih[l][k][r] = p.wih[l][i];
        }
        { int i = tid; whh[l][i & 7][i >> 3] = p.whh[l][i]; }  // 256 elems exactly
        if (tid < 32) bs[l][tid] = p.bih[l][tid] + p.bhh[l][tid];
    }
    const int e0 = blockIdx.x * 32;
    for (int i = tid; i < 32 * 168; i += 256)
        (&xs[0][0])[i] = x[(size_t)e0 * 168 + i];
    __syncthreads();

    const int el = tid >> 3, j = tid & 7;
    float h0 = 0.f, c0 = 0.f, h1 = 0.f, c1 = 0.f, h2 = 0.f, c2 = 0.f, h3 = 0.f, c3 = 0.f;

    for (int t = 0; t < 24; ++t) {
        // layer 0 (in = 7 from x)
        {
            float ai = bs[0][j], af = bs[0][8 + j], ag = bs[0][16 + j], ao = bs[0][24 + j];
#pragma unroll
            for (int k = 0; k < 7; ++k) {
                float xv = xs[el][t * 7 + k];
                ai += wih[0][k][j] * xv;
                af += wih[0][k][8 + j] * xv;
                ag += wih[0][k][16 + j] * xv;
                ao += wih[0][k][24 + j] * xv;
            }
#pragma unroll
            for (int k = 0; k < 8; ++k) {
                float hv = __shfl(h0, k, 8);
                ai += whh[0][k][j] * hv;
                af += whh[0][k][8 + j] * hv;
                ag += whh[0][k][16 + j] * hv;
                ao += whh[0][k][24 + j] * hv;
            }
            c0 = sigm(af) * c0 + sigm(ai) * tanh_(ag);
            h0 = sigm(ao) * tanh_(c0);
        }
        lstm_step_upper(wih[1], whh[1], bs[1], j, h0, h1, c1);
        lstm_step_upper(wih[2], whh[2], bs[2], j, h1, h2, c2);
        lstm_step_upper(wih[3], whh[3], bs[3], j, h2, h3, c3);
        // Y[b][t*8+j]
        Y[((size_t)(e0 + el) * 24 + t) * 8 + j] = f2bf(h3);
    }
}

// ---------------------------------------------------------------- GEMM ----
// C[m,n] = relu(A[m,:] . W[n,:] + bias[n]); A bf16 [M,K], W fp32 [N,K].
// FUSE3: instead of storing C, compute out[m,0:4] += C_tile @ W3^T via LDS + atomics.
template <int KDIM, bool FUSE3>
__global__ __launch_bounds__(256) void gemm_kernel(const ushort* __restrict__ A,
                                                   const float* __restrict__ W,
                                                   const float* __restrict__ bias,
                                                   ushort* __restrict__ Hout,
                                                   const float* __restrict__ W3,
                                                   float* __restrict__ outf, int N) {
    constexpr int SMEM = FUSE3 ? (128 * 130) : (128 * 80);  // ushorts
    __shared__ ushort smem[SMEM];
    __shared__ float w3s[FUSE3 ? 512 : 1];
    ushort* As = smem;            // [128][40] padded, k-contig rows
    ushort* Ws = smem + 5120;     // [128][40]

    const int tid = threadIdx.x;
    const int m0 = blockIdx.x * 128;
    const int n0 = blockIdx.y * 128;
    const int lane = tid & 63;
    const int wv = tid >> 6;
    const int wm = (wv & 1) * 64;
    const int wn = (wv >> 1) * 64;
    const int m16 = lane & 15;
    const int quad = lane >> 4;
    const int row_h = tid >> 1, half = tid & 1;   // staging map: 2 threads/row, 32B each

    if (FUSE3) {
        for (int i = tid; i < 512; i += 256)
            w3s[i] = W3[(size_t)(i >> 7) * 2048 + n0 + (i & 127)];
    }

    f32x4 acc[4][4];
    const f32x4 zero = {0.f, 0.f, 0.f, 0.f};
#pragma unroll
    for (int mi = 0; mi < 4; ++mi)
#pragma unroll
        for (int ni = 0; ni < 4; ++ni) acc[mi][ni] = zero;

    for (int k0 = 0; k0 < KDIM; k0 += 32) {
        // stage A (bf16): row_h, 16 ushorts at half*16
        const uint4* asrc = (const uint4*)(A + (size_t)(m0 + row_h) * KDIM + k0 + half * 16);
        uint4 a0 = asrc[0], a1 = asrc[1];
        // stage W (fp32 -> bf16): 16 floats
        const float4* wsrc = (const float4*)(W + (size_t)(n0 + row_h) * KDIM + k0 + half * 16);
        float4 w0 = wsrc[0], w1 = wsrc[1], w2 = wsrc[2], w3v = wsrc[3];

        uint4* ad = (uint4*)&As[row_h * 40 + half * 16];
        ad[0] = a0; ad[1] = a1;

        uint4 pa, pb;
        pa.x = (uint)f2bf(w0.x) | ((uint)f2bf(w0.y) << 16);
        pa.y = (uint)f2bf(w0.z) | ((uint)f2bf(w0.w) << 16);
        pa.z = (uint)f2bf(w1.x) | ((uint)f2bf(w1.y) << 16);
        pa.w = (uint)f2bf(w1.z) | ((uint)f2bf(w1.w) << 16);
        pb.x = (uint)f2bf(w2.x) | ((uint)f2bf(w2.y) << 16);
        pb.y = (uint)f2bf(w2.z) | ((uint)f2bf(w2.w) << 16);
        pb.z = (uint)f2bf(w3v.x) | ((uint)f2bf(w3v.y) << 16);
        pb.w = (uint)f2bf(w3v.z) | ((uint)f2bf(w3v.w) << 16);
        uint4* wd = (uint4*)&Ws[row_h * 40 + half * 16];
        wd[0] = pa; wd[1] = pb;
        __syncthreads();

        bf16x8 afr[4], bfr[4];
#pragma unroll
        for (int mi = 0; mi < 4; ++mi)
            afr[mi] = *(const bf16x8*)&As[(wm + mi * 16 + m16) * 40 + quad * 8];
#pragma unroll
        for (int ni = 0; ni < 4; ++ni)
            bfr[ni] = *(const bf16x8*)&Ws[(wn + ni * 16 + m16) * 40 + quad * 8];
#pragma unroll
        for (int mi = 0; mi < 4; ++mi)
#pragma unroll
            for (int ni = 0; ni < 4; ++ni)
                acc[mi][ni] = __builtin_amdgcn_mfma_f32_16x16x32_bf16(afr[mi], bfr[ni],
                                                                     acc[mi][ni], 0, 0, 0);
        __syncthreads();
    }

    if (!FUSE3) {
#pragma unroll
        for (int ni = 0; ni < 4; ++ni) {
            const int col = n0 + wn + ni * 16 + m16;
            const float b = bias[col];
#pragma unroll
            for (int mi = 0; mi < 4; ++mi)
#pragma unroll
                for (int r = 0; r < 4; ++r) {
                    const int row = m0 + wm + mi * 16 + quad * 4 + r;
                    float v = acc[mi][ni][r] + b;
                    Hout[(size_t)row * N + col] = f2bf(fmaxf(v, 0.f));
                }
        }
    } else {
        // relu'd tile -> LDS (stride 130: column-scans are conflict-free), then 128-col
        // partial dots against W3 slice, atomicAdd into out.
        ushort* Cs = smem;
#pragma unroll
        for (int ni = 0; ni < 4; ++ni) {
            const int cl = wn + ni * 16 + m16;
            const float b = bias[n0 + cl];
#pragma unroll
            for (int mi = 0; mi < 4; ++mi)
#pragma unroll
                for (int r = 0; r < 4; ++r) {
                    const int rl = wm + mi * 16 + quad * 4 + r;
                    float v = acc[mi][ni][r] + b;
                    Cs[rl * 130 + cl] = f2bf(fmaxf(v, 0.f));
                }
        }
        __syncthreads();
        const int r = tid & 127;
        const int na = tid >> 7;   // thread covers n = na and na+2 for row r
        float p0 = 0.f, p1 = 0.f;
#pragma unroll 4
        for (int c = 0; c < 128; ++c) {
            float v = bf2f(Cs[r * 130 + c]);
            p0 += v * w3s[na * 128 + c];
            p1 += v * w3s[(na + 2) * 128 + c];
        }
        atomicAdd(&outf[(size_t)(m0 + r) * 4 + na], p0);
        atomicAdd(&outf[(size_t)(m0 + r) * 4 + na + 2], p1);
    }
}

__global__ __launch_bounds__(256) void init_out(float* __restrict__ out,
                                                const float* __restrict__ b3) {
    const int i = blockIdx.x * 256 + threadIdx.x;
    if (i < 16384 * 4) out[i] = b3[i & 3];
}

// -------------------------------------------------------------- launch ----
extern "C" void kernel_launch(void* const* d_in, const int* in_sizes, int n_in,
                              void* d_out, int out_size, void* d_ws, size_t ws_size,
                              hipStream_t stream) {
    const float* x = (const float*)d_in[0];
    LstmW w;
    for (int l = 0; l < 4; ++l) {
        w.wih[l] = (const float*)d_in[1 + 4 * l];
        w.whh[l] = (const float*)d_in[2 + 4 * l];
        w.bih[l] = (const float*)d_in[3 + 4 * l];
        w.bhh[l] = (const float*)d_in[4 + 4 * l];
    }
    const float* Wd1 = (const float*)d_in[17];
    const float* bd1 = (const float*)d_in[18];
    const float* Wd2 = (const float*)d_in[19];
    const float* bd2 = (const float*)d_in[20];
    const float* Wd3 = (const float*)d_in[21];
    const float* bd3 = (const float*)d_in[22];
    float* out = (float*)d_out;

    ushort* Y  = (ushort*)d_ws;                          // 16384*192 bf16
    ushort* H1 = (ushort*)((char*)d_ws + 6291456);       // 16384*1024 bf16

    lstm_kernel<<<512, 256, 0, stream>>>(x, w, Y);
    gemm_kernel<192, false><<<dim3(128, 8), 256, 0, stream>>>(Y, Wd1, bd1, H1, nullptr, nullptr, 1024);
    init_out<<<256, 256, 0, stream>>>(out, bd3);
    gemm_kernel<1024, true><<<dim3(128, 16), 256, 0, stream>>>(H1, Wd2, bd2, nullptr, Wd3, out, 2048);
}

// Round 2
// 272.050 us; speedup vs baseline: 1.3143x; 1.3143x over previous
//
#include <hip/hip_runtime.h>
#include <hip/hip_bf16.h>

// LSTM_80960133529703: B=16384, T=24, F=7, H=8, L=4; dense 192->1024->2048->4.
// R2: (a) pre-convert dense weights fp32->bf16 once; (b) GEMMs staged via
// __builtin_amdgcn_global_load_lds width=16 (m97 structure, unpadded [128][32]);
// (c) LSTM: weight columns in VGPRs, recurrence through padded LDS h-buffer
// (1 ds_write + 4 ds_read_b128 per t-layer instead of ~64 b32 + 16 bpermute).
// ws: Y bf16 [16384,192] @0 (6.29MB) | H1 bf16 [16384,1024] @6291456 (33.55MB)
//     W1b @39845888 (384KB) | W2b @40239104 (4MB) | W3b @44433408 (16KB)

typedef __attribute__((ext_vector_type(4))) float f32x4;
typedef __attribute__((ext_vector_type(8))) short bf16x8;

__device__ __forceinline__ ushort f2bf(float f) {
    union { float f; uint u; } v; v.f = f;
    uint u = v.u;
    return (ushort)((u + 0x7fffu + ((u >> 16) & 1u)) >> 16);   // RNE
}
__device__ __forceinline__ float bf2f(ushort h) {
    union { uint u; float f; } v; v.u = ((uint)h) << 16;
    return v.f;
}
__device__ __forceinline__ float sigm(float x) { return 1.0f / (1.0f + __expf(-x)); }
__device__ __forceinline__ float tanh_(float x) { return 2.0f / (1.0f + __expf(-2.0f * x)) - 1.0f; }

// async global->LDS, 16 B/lane; LDS dest = wave-uniform base + lane*16.
typedef const __attribute__((address_space(1))) unsigned int ga_u32;
typedef __attribute__((address_space(3))) unsigned int lds_u32;
__device__ __forceinline__ void g2l16(const void* g, void* l) {
    __builtin_amdgcn_global_load_lds((ga_u32*)(unsigned long long)g,
                                     (lds_u32*)(unsigned int)(unsigned long long)l,
                                     16, 0, 0);
}

// ------------------------------------------------------------ weight cvt ----
// W1 1024x192 (49152 f4), W2 2048x1024 (524288 f4), W3 4x2048 (2048 f4).
__global__ __launch_bounds__(256) void cvt_weights(const float* __restrict__ W1,
                                                   const float* __restrict__ W2,
                                                   const float* __restrict__ W3,
                                                   ushort* __restrict__ W1b,
                                                   ushort* __restrict__ W2b,
                                                   ushort* __restrict__ W3b) {
    int i = blockIdx.x * 256 + threadIdx.x;   // float4 index, total 575488 exact
    const float4* s; ushort* d; int off;
    if (i < 49152) { s = (const float4*)W1; d = W1b; off = i; }
    else if (i < 49152 + 524288) { s = (const float4*)W2; d = W2b; off = i - 49152; }
    else { s = (const float4*)W3; d = W3b; off = i - 573440; }
    float4 v = s[off];
    ushort4 r; r.x = f2bf(v.x); r.y = f2bf(v.y); r.z = f2bf(v.z); r.w = f2bf(v.w);
    ((ushort4*)d)[off] = r;
}

// ---------------------------------------------------------------- LSTM ----
struct LstmW {
    const float* wih[4];
    const float* whh[4];
    const float* bih[4];
    const float* bhh[4];
};

__device__ __forceinline__ void gates8(const float wx[4][8], const float xv8[8],
                                       float& a0, float& a1, float& a2, float& a3) {
#pragma unroll
    for (int k = 0; k < 8; ++k) {
        float xv = xv8[k];
        a0 += wx[0][k] * xv; a1 += wx[1][k] * xv;
        a2 += wx[2][k] * xv; a3 += wx[3][k] * xv;
    }
}
__device__ __forceinline__ void cellup(float a0, float a1, float a2, float a3,
                                       float& h, float& c) {
    c = sigm(a1) * c + sigm(a0) * tanh_(a2);
    h = sigm(a3) * tanh_(c);
}
__device__ __forceinline__ void ld8(const float* p, float v[8]) {
    float4 a = *(const float4*)p;
    float4 b = *(const float4*)(p + 4);
    v[0] = a.x; v[1] = a.y; v[2] = a.z; v[3] = a.w;
    v[4] = b.x; v[5] = b.y; v[6] = b.z; v[7] = b.w;
}

__global__ __launch_bounds__(256) void lstm_kernel(const float* __restrict__ x, LstmW p,
                                                   ushort* __restrict__ Y) {
    __shared__ float xs[32 * 168];   // 32 elems x 168 inputs
    __shared__ float hb[32 * 200];   // per-elem 24*8 floats, stride 200 (2-way banks)

    const int tid = threadIdx.x;
    const int e0 = blockIdx.x * 32;
    {
        const float4* s = (const float4*)(x + (size_t)e0 * 168);
        float4* d = (float4*)xs;
        for (int i = tid; i < 1344; i += 256) d[i] = s[i];
    }
    __syncthreads();

    const int el = tid >> 3, j = tid & 7;
    float* hr = hb + el * 200;
    const float* xr = xs + el * 168;

    float wx[4][8], wh[4][8], bs4[4];

    // ---- layer 0 (in = 7, from xs) ----
    {
        const float* Wih = p.wih[0];
        const float* Whh = p.whh[0];
#pragma unroll
        for (int g = 0; g < 4; ++g) {
#pragma unroll
            for (int k = 0; k < 7; ++k) wx[g][k] = Wih[(g * 8 + j) * 7 + k];
#pragma unroll
            for (int k = 0; k < 8; ++k) wh[g][k] = Whh[(g * 8 + j) * 8 + k];
            bs4[g] = p.bih[0][g * 8 + j] + p.bhh[0][g * 8 + j];
        }
        float h = 0.f, c = 0.f;
        // t = 0
        {
            float a0 = bs4[0], a1 = bs4[1], a2 = bs4[2], a3 = bs4[3];
#pragma unroll
            for (int k = 0; k < 7; ++k) {
                float xv = xr[k];
                a0 += wx[0][k] * xv; a1 += wx[1][k] * xv;
                a2 += wx[2][k] * xv; a3 += wx[3][k] * xv;
            }
            cellup(a0, a1, a2, a3, h, c);
            hr[j] = h;
        }
        for (int t = 1; t < 24; ++t) {
            float a0 = bs4[0], a1 = bs4[1], a2 = bs4[2], a3 = bs4[3];
#pragma unroll
            for (int k = 0; k < 7; ++k) {
                float xv = xr[t * 7 + k];
                a0 += wx[0][k] * xv; a1 += wx[1][k] * xv;
                a2 += wx[2][k] * xv; a3 += wx[3][k] * xv;
            }
            float hp[8]; ld8(&hr[(t - 1) * 8], hp);
            gates8(wh, hp, a0, a1, a2, a3);
            cellup(a0, a1, a2, a3, h, c);
            hr[t * 8 + j] = h;
        }
    }

    // ---- layers 1..3 (in = 8, from hb; recurrence via hb slot t-1) ----
#pragma unroll
    for (int l = 1; l < 4; ++l) {
        const float* Wih = p.wih[l];
        const float* Whh = p.whh[l];
#pragma unroll
        for (int g = 0; g < 4; ++g) {
#pragma unroll
            for (int k = 0; k < 8; ++k) {
                wx[g][k] = Wih[(g * 8 + j) * 8 + k];
                wh[g][k] = Whh[(g * 8 + j) * 8 + k];
            }
            bs4[g] = p.bih[l][g * 8 + j] + p.bhh[l][g * 8 + j];
        }
        float h = 0.f, c = 0.f;
        // t = 0
        {
            float xin[8]; ld8(&hr[0], xin);       // layer l-1 output at t=0
            float a0 = bs4[0], a1 = bs4[1], a2 = bs4[2], a3 = bs4[3];
            gates8(wx, xin, a0, a1, a2, a3);
            cellup(a0, a1, a2, a3, h, c);
            hr[j] = h;                             // overwrite slot 0 with layer-l h
            if (l == 3) Y[((size_t)(e0 + el) * 24) * 8 + j] = f2bf(h);
        }
        for (int t = 1; t < 24; ++t) {
            float xin[8]; ld8(&hr[t * 8], xin);          // layer l-1, time t
            float hp[8];  ld8(&hr[(t - 1) * 8], hp);     // layer l,   time t-1
            float a0 = bs4[0], a1 = bs4[1], a2 = bs4[2], a3 = bs4[3];
            gates8(wx, xin, a0, a1, a2, a3);
            gates8(wh, hp, a0, a1, a2, a3);
            cellup(a0, a1, a2, a3, h, c);
            hr[t * 8 + j] = h;
            if (l == 3) Y[((size_t)(e0 + el) * 24 + t) * 8 + j] = f2bf(h);
        }
    }
}

// ---------------------------------------------------------------- GEMM ----
// C[m,n] = relu(A[m,:] . W[n,:] + bias[n]); A,W bf16 row-major, K-contig.
// m97 staging: unpadded [128][32] ushorts; wave wv stages 16 rows per call,
// LDS dest = uniform base + lane*16 (row=lane/4, colchunk=lane%4).
template <int KDIM, bool FUSE3>
__global__ __launch_bounds__(256) void gemm_kernel(const ushort* __restrict__ A,
                                                   const ushort* __restrict__ W,
                                                   const float* __restrict__ bias,
                                                   ushort* __restrict__ Hout,
                                                   const float* __restrict__ W3,
                                                   float* __restrict__ outf, int N) {
    constexpr int SMEMN = FUSE3 ? (128 * 136) : 8192;  // Cs overlay needs 34816 B
    __shared__ ushort smem[SMEMN];
    __shared__ float w3s[FUSE3 ? 512 : 1];
    ushort* As = smem;            // [128][32]
    ushort* Ws = smem + 4096;     // [128][32]

    const int tid = threadIdx.x;
    const int m0 = blockIdx.x * 128;
    const int n0 = blockIdx.y * 128;
    const int lane = tid & 63;
    const int wv = tid >> 6;
    const int wm = (wv & 1) * 64;
    const int wn = (wv >> 1) * 64;
    const int m16 = lane & 15;
    const int quad = lane >> 4;

    if (FUSE3) {
        for (int i = tid; i < 512; i += 256)
            w3s[i] = W3[(size_t)(i >> 7) * 2048 + n0 + (i & 127)];
    }

    f32x4 acc[4][4];
    const f32x4 zero = {0.f, 0.f, 0.f, 0.f};
#pragma unroll
    for (int mi = 0; mi < 4; ++mi)
#pragma unroll
        for (int ni = 0; ni < 4; ++ni) acc[mi][ni] = zero;

    const int srow = wv * 16 + (lane >> 2);            // staging row in half-tile
    const ushort* Ag = A + (size_t)(m0 + srow) * KDIM + (lane & 3) * 8;
    const ushort* Wg = W + (size_t)(n0 + srow) * KDIM + (lane & 3) * 8;
    ushort* Ald = As + wv * 512;
    ushort* Wld = Ws + wv * 512;

    for (int k0 = 0; k0 < KDIM; k0 += 32) {
        g2l16(Ag + k0, Ald);
        g2l16(Ag + (size_t)64 * KDIM + k0, Ald + 2048);
        g2l16(Wg + k0, Wld);
        g2l16(Wg + (size_t)64 * KDIM + k0, Wld + 2048);
        __syncthreads();

        bf16x8 afr[4], bfr[4];
#pragma unroll
        for (int mi = 0; mi < 4; ++mi)
            afr[mi] = *(const bf16x8*)&As[(wm + mi * 16 + m16) * 32 + quad * 8];
#pragma unroll
        for (int ni = 0; ni < 4; ++ni)
            bfr[ni] = *(const bf16x8*)&Ws[(wn + ni * 16 + m16) * 32 + quad * 8];
#pragma unroll
        for (int mi = 0; mi < 4; ++mi)
#pragma unroll
            for (int ni = 0; ni < 4; ++ni)
                acc[mi][ni] = __builtin_amdgcn_mfma_f32_16x16x32_bf16(afr[mi], bfr[ni],
                                                                     acc[mi][ni], 0, 0, 0);
        __syncthreads();
    }

    if (!FUSE3) {
#pragma unroll
        for (int ni = 0; ni < 4; ++ni) {
            const int col = n0 + wn + ni * 16 + m16;
            const float b = bias[col];
#pragma unroll
            for (int mi = 0; mi < 4; ++mi)
#pragma unroll
                for (int r = 0; r < 4; ++r) {
                    const int row = m0 + wm + mi * 16 + quad * 4 + r;
                    Hout[(size_t)row * N + col] = f2bf(fmaxf(acc[mi][ni][r] + b, 0.f));
                }
        }
    } else {
        // relu'd bf16 tile -> Cs (stride 136: 16B-aligned rows), vectorized dot
        // against w3s, 2 atomicAdds/thread.
        ushort* Cs = smem;
#pragma unroll
        for (int ni = 0; ni < 4; ++ni) {
            const int cl = wn + ni * 16 + m16;
            const float b = bias[n0 + cl];
#pragma unroll
            for (int mi = 0; mi < 4; ++mi)
#pragma unroll
                for (int r = 0; r < 4; ++r) {
                    const int rl = wm + mi * 16 + quad * 4 + r;
                    Cs[rl * 136 + cl] = f2bf(fmaxf(acc[mi][ni][r] + b, 0.f));
                }
        }
        __syncthreads();
        const int r = tid & 127;
        const int na = tid >> 7;
        const ushort* crow = &Cs[r * 136];
        float p0 = 0.f, p1 = 0.f;
#pragma unroll
        for (int ch = 0; ch < 16; ++ch) {
            bf16x8 v = *(const bf16x8*)(crow + ch * 8);
#pragma unroll
            for (int q = 0; q < 8; ++q) {
                float f = bf2f((ushort)v[q]);
                p0 += f * w3s[na * 128 + ch * 8 + q];
                p1 += f * w3s[(na + 2) * 128 + ch * 8 + q];
            }
        }
        atomicAdd(&outf[(size_t)(m0 + r) * 4 + na], p0);
        atomicAdd(&outf[(size_t)(m0 + r) * 4 + na + 2], p1);
    }
}

__global__ __launch_bounds__(256) void init_out(float* __restrict__ out,
                                                const float* __restrict__ b3) {
    const int i = blockIdx.x * 256 + threadIdx.x;
    if (i < 16384 * 4) out[i] = b3[i & 3];
}

// -------------------------------------------------------------- launch ----
extern "C" void kernel_launch(void* const* d_in, const int* in_sizes, int n_in,
                              void* d_out, int out_size, void* d_ws, size_t ws_size,
                              hipStream_t stream) {
    const float* x = (const float*)d_in[0];
    LstmW w;
    for (int l = 0; l < 4; ++l) {
        w.wih[l] = (const float*)d_in[1 + 4 * l];
        w.whh[l] = (const float*)d_in[2 + 4 * l];
        w.bih[l] = (const float*)d_in[3 + 4 * l];
        w.bhh[l] = (const float*)d_in[4 + 4 * l];
    }
    const float* Wd1 = (const float*)d_in[17];
    const float* bd1 = (const float*)d_in[18];
    const float* Wd2 = (const float*)d_in[19];
    const float* bd2 = (const float*)d_in[20];
    const float* Wd3 = (const float*)d_in[21];
    const float* bd3 = (const float*)d_in[22];
    float* out = (float*)d_out;

    ushort* Y   = (ushort*)d_ws;                          // 6,291,456 B
    ushort* H1  = (ushort*)((char*)d_ws + 6291456);       // 33,554,432 B
    ushort* W1b = (ushort*)((char*)d_ws + 39845888);      // 393,216 B
    ushort* W2b = (ushort*)((char*)d_ws + 40239104);      // 4,194,304 B
    ushort* W3b = (ushort*)((char*)d_ws + 44433408);      // 16,384 B

    cvt_weights<<<2248, 256, 0, stream>>>(Wd1, Wd2, Wd3, W1b, W2b, W3b);
    lstm_kernel<<<512, 256, 0, stream>>>(x, w, Y);
    gemm_kernel<192, false><<<dim3(128, 8), 256, 0, stream>>>(Y, W1b, bd1, H1, nullptr, nullptr, 1024);
    init_out<<<256, 256, 0, stream>>>(out, bd3);
    gemm_kernel<1024, true><<<dim3(128, 16), 256, 0, stream>>>(H1, W2b, bd2, nullptr, Wd3, out, 2048);
}